// Round 2
// baseline (587.663 us; speedup 1.0000x reference)
//
#include <hip/hip_runtime.h>
#include <hip/hip_bf16.h>

#define B_DIM 4096
#define C_DIM 1024
#define N_DIM 256
#define M_DIM 64
#define GPAD  208   // padded gate count (13 MFMA n-tiles of 16)
#define NG    198   // real gates: 64 k | 1 beta | 1 g | 3 s | 1 gamma | 64 e | 64 a
#define EPSC  1e-8f
#define SMS   68    // LDS row stride in floats: 64 + 4 pad (float4-aligned, bank-uniform)

typedef __attribute__((ext_vector_type(8))) short bfrag_t;  // 8 bf16 (4 VGPRs)
typedef __attribute__((ext_vector_type(4))) float ffrag_t;  // 4 fp32 acc

__device__ __forceinline__ short f2b(float f) {
    __hip_bfloat16 h = __float2bfloat16(f);
    return *reinterpret_cast<short*>(&h);
}
__device__ __forceinline__ float softplus_f(float x) {
    return fmaxf(x, 0.f) + log1pf(expf(-fabsf(x)));
}
__device__ __forceinline__ float sigmoid_f(float x) {
    return 1.f / (1.f + expf(-x));
}
__device__ __forceinline__ float warp_red_max(float v) {
#pragma unroll
    for (int off = 32; off; off >>= 1) v = fmaxf(v, __shfl_xor(v, off));
    return v;
}
__device__ __forceinline__ float warp_red_sum(float v) {
#pragma unroll
    for (int off = 32; off; off >>= 1) v += __shfl_xor(v, off);
    return v;
}

// ---------------------------------------------------------------------------
// Kernel 0: pack 7 fp32 weight matrices -> one bf16 Wcat[GPAD][C_DIM] in ws.
// Rows 198..207 are zeroed so kernel 1 can run branch-free over 13 tiles.
// ---------------------------------------------------------------------------
__global__ __launch_bounds__(256) void build_wcat(
    const float* __restrict__ Wk, const float* __restrict__ Wbeta,
    const float* __restrict__ Wg, const float* __restrict__ Ws,
    const float* __restrict__ Wgamma, const float* __restrict__ We,
    const float* __restrict__ Wa, short* __restrict__ wcat)
{
    int idx = blockIdx.x * 256 + threadIdx.x;
    if (idx >= GPAD * C_DIM) return;
    int n = idx >> 10, k = idx & (C_DIM - 1);
    float v;
    if (n < 64)        v = Wk[n * C_DIM + k];
    else if (n == 64)  v = Wbeta[k];
    else if (n == 65)  v = Wg[k];
    else if (n < 69)   v = Ws[(n - 66) * C_DIM + k];
    else if (n == 69)  v = Wgamma[k];
    else if (n < 134)  v = We[(n - 70) * C_DIM + k];
    else if (n < NG)   v = Wa[(n - 134) * C_DIM + k];
    else               v = 0.f;
    wcat[idx] = f2b(v);
}

// ---------------------------------------------------------------------------
// Kernel 1: gates GEMM  pre[b, n] = emb[b,:] . Wcat[n,:]  (raw, no bias/act)
// One wave per block: 16 batch rows x 208 gate cols via 13 MFMA n-tiles.
// A: fp32 emb loaded as 2x float4, converted inline to bf16 fragments.
// B: bf16 Wcat rows, direct 16B fragment loads (k-contiguous per lane).
// ---------------------------------------------------------------------------
__global__ __launch_bounds__(64) void gates_gemm(
    const float* __restrict__ emb,
    const short* __restrict__ wcat,
    float* __restrict__ gates)
{
    const int lane = threadIdx.x;          // 0..63
    const int row0 = blockIdx.x << 4;      // 16 batch rows per block
    const int m    = lane & 15;
    const int ko   = (lane >> 4) << 3;     // k sub-offset 0/8/16/24 (quad*8)

    const float* arow = emb + (size_t)(row0 + m) * C_DIM + ko;
    const short* brow = wcat + m * C_DIM + ko;   // tile t adds t*16*C_DIM

    ffrag_t acc[13];
#pragma unroll
    for (int t = 0; t < 13; ++t) acc[t] = (ffrag_t)(0.f);

    for (int k = 0; k < C_DIM; k += 32) {
        float4 a0 = *(const float4*)(arow + k);
        float4 a1 = *(const float4*)(arow + k + 4);
        bfrag_t af;
        af[0] = f2b(a0.x); af[1] = f2b(a0.y); af[2] = f2b(a0.z); af[3] = f2b(a0.w);
        af[4] = f2b(a1.x); af[5] = f2b(a1.y); af[6] = f2b(a1.z); af[7] = f2b(a1.w);
#pragma unroll
        for (int t = 0; t < 13; ++t) {
            bfrag_t bf = *(const bfrag_t*)(brow + t * (16 * C_DIM) + k);
            acc[t] = __builtin_amdgcn_mfma_f32_16x16x32_bf16(af, bf, acc[t], 0, 0, 0);
        }
    }

    // C/D layout (m89-verified): col(n) = lane&15, row(m) = (lane>>4)*4 + reg
    const int crow = row0 + ((lane >> 4) << 2);
#pragma unroll
    for (int t = 0; t < 13; ++t) {
        int n = (t << 4) + m;
#pragma unroll
        for (int r = 0; r < 4; ++r)
            gates[(size_t)(crow + r) * GPAD + n] = acc[t][r];
    }
}

// ---------------------------------------------------------------------------
// Kernel 2: fused NTM write head. One block (256 threads) per batch row.
// memory[b] staged once to LDS (fp32, stride 68 = bank-uniform for float4).
// ---------------------------------------------------------------------------
__global__ __launch_bounds__(256) void ntm_fused(
    const float* __restrict__ w_prev,    // [B,N]
    const float* __restrict__ memory,    // [B,N,M]
    const float* __restrict__ gates,     // [B,GPAD] raw pre-activations
    const float* __restrict__ bk, const float* __restrict__ bbeta,
    const float* __restrict__ bg, const float* __restrict__ bs,
    const float* __restrict__ bgamma, const float* __restrict__ be,
    const float* __restrict__ ba,
    float* __restrict__ out_w,           // [B,N]
    float* __restrict__ out_mem)         // [B,N,M]
{
    const int b = blockIdx.x;
    const int t = threadIdx.x;

    __shared__ __align__(16) float sm[N_DIM * SMS];   // 69.6 KB memory tile
    __shared__ __align__(16) float pre[GPAD];
    __shared__ __align__(16) float kvf[M_DIM];
    __shared__ __align__(16) float ev[M_DIM];
    __shared__ __align__(16) float av[M_DIM];
    __shared__ __align__(16) float wgs[N_DIM];
    __shared__ __align__(16) float wsh[N_DIM];
    __shared__ float scal[8];   // 0 beta, 1 g, 2 gamma, 3..5 s, 6 k_norm
    __shared__ float redA[4], redB[4], redC[4];

    float wprev_t = w_prev[(size_t)b * N_DIM + t];

    // ---- stage memory[b] -> LDS (coalesced float4) ----
    const float4* msrc = (const float4*)(memory + (size_t)b * (N_DIM * M_DIM));
#pragma unroll
    for (int i = 0; i < 16; ++i) {
        int q = t + (i << 8);             // 0..4095 float4s
        float4 v = msrc[q];
        int n = q >> 4, c4 = q & 15;      // 16 float4 per 64-float row
        *(float4*)&sm[n * SMS + (c4 << 2)] = v;
    }
    if (t < GPAD) pre[t] = gates[(size_t)b * GPAD + t];
    __syncthreads();

    // ---- activations ----
    if (t < 64) {
        float kt = pre[t] + bk[t];
        kvf[t] = kt;
        ev[t]  = sigmoid_f(pre[70 + t] + be[t]);
        av[t]  = pre[134 + t] + ba[t];
        float sq = warp_red_sum(kt * kt);
        if (t == 0) scal[6] = sqrtf(sq);
    }
    if (t == 64) {
        scal[0] = softplus_f(pre[64] + bbeta[0]);           // beta
        scal[1] = sigmoid_f(pre[65] + bg[0]);               // g
        float x0 = pre[66] + bs[0];
        float x1 = pre[67] + bs[1];
        float x2 = pre[68] + bs[2];
        float mx = fmaxf(x0, fmaxf(x1, x2));
        float e0 = expf(x0 - mx), e1 = expf(x1 - mx), e2 = expf(x2 - mx);
        float inv = 1.f / (e0 + e1 + e2);
        scal[3] = e0 * inv; scal[4] = e1 * inv; scal[5] = e2 * inv;
        scal[2] = 1.f + softplus_f(pre[69] + bgamma[0]);    // gamma
    }
    __syncthreads();

    // ---- content addressing: cosine similarity for row t ----
    float dot = 0.f, nrm = 0.f;
    const float4* kv4 = (const float4*)kvf;
#pragma unroll
    for (int j = 0; j < 16; ++j) {
        float4 mv = *(const float4*)&sm[t * SMS + (j << 2)];
        float4 kj = kv4[j];
        dot = fmaf(mv.x, kj.x, dot); dot = fmaf(mv.y, kj.y, dot);
        dot = fmaf(mv.z, kj.z, dot); dot = fmaf(mv.w, kj.w, dot);
        nrm = fmaf(mv.x, mv.x, nrm); nrm = fmaf(mv.y, mv.y, nrm);
        nrm = fmaf(mv.z, mv.z, nrm); nrm = fmaf(mv.w, mv.w, nrm);
    }
    float cosv = dot / (fmaxf(sqrtf(nrm), EPSC) * fmaxf(scal[6], EPSC));
    float x = scal[0] * cosv;   // beta * cos

    // ---- softmax over N=256 (one value per thread) ----
    float mx = warp_red_max(x);
    if ((t & 63) == 0) redA[t >> 6] = mx;
    __syncthreads();
    mx = fmaxf(fmaxf(redA[0], redA[1]), fmaxf(redA[2], redA[3]));
    float ex = expf(x - mx);
    float sm_ = warp_red_sum(ex);
    if ((t & 63) == 0) redB[t >> 6] = sm_;
    __syncthreads();
    float wc = ex / (redB[0] + redB[1] + redB[2] + redB[3]);

    // ---- interpolation gate ----
    float g = scal[1];
    float wg = g * wc + (1.f - g) * wprev_t;
    wgs[t] = wg;
    __syncthreads();

    // ---- circular 3-tap shift ----
    float ws_ = scal[3] * wgs[(t + 255) & 255] + scal[4] * wg + scal[5] * wgs[(t + 1) & 255];

    // ---- sharpen ----
    float wp = powf(fmaxf(ws_, 0.f), scal[2]);
    float ts = warp_red_sum(wp);
    if ((t & 63) == 0) redC[t >> 6] = ts;
    __syncthreads();
    float w = wp / (redC[0] + redC[1] + redC[2] + redC[3] + 1e-16f);

    out_w[(size_t)b * N_DIM + t] = w;
    wsh[t] = w;
    __syncthreads();

    // ---- erase/add write, float4-coalesced ----
    float4* omem = (float4*)(out_mem + (size_t)b * (N_DIM * M_DIM));
    const float4* ev4 = (const float4*)ev;
    const float4* av4 = (const float4*)av;
#pragma unroll
    for (int i = 0; i < 16; ++i) {
        int q = t + (i << 8);
        int n = q >> 4, c4 = q & 15;
        float4 mv = *(const float4*)&sm[n * SMS + (c4 << 2)];
        float wn = wsh[n];
        float4 e4 = ev4[c4];
        float4 a4 = av4[c4];
        float4 r;
        r.x = fmaf(mv.x, -wn * e4.x, fmaf(wn, a4.x, mv.x));  // m*(1-w e) + w a
        r.y = fmaf(mv.y, -wn * e4.y, fmaf(wn, a4.y, mv.y));
        r.z = fmaf(mv.z, -wn * e4.z, fmaf(wn, a4.z, mv.z));
        r.w = fmaf(mv.w, -wn * e4.w, fmaf(wn, a4.w, mv.w));
        omem[q] = r;
    }
}

extern "C" void kernel_launch(void* const* d_in, const int* in_sizes, int n_in,
                              void* d_out, int out_size, void* d_ws, size_t ws_size,
                              hipStream_t stream) {
    const float* emb    = (const float*)d_in[0];
    const float* w_prev = (const float*)d_in[1];
    const float* memory = (const float*)d_in[2];
    const float* Wk     = (const float*)d_in[3];
    const float* bk     = (const float*)d_in[4];
    const float* Wbeta  = (const float*)d_in[5];
    const float* bbeta  = (const float*)d_in[6];
    const float* Wg     = (const float*)d_in[7];
    const float* bg     = (const float*)d_in[8];
    const float* Ws     = (const float*)d_in[9];
    const float* bs     = (const float*)d_in[10];
    const float* Wgamma = (const float*)d_in[11];
    const float* bgamma = (const float*)d_in[12];
    const float* We     = (const float*)d_in[13];
    const float* be     = (const float*)d_in[14];
    const float* Wa     = (const float*)d_in[15];
    const float* ba     = (const float*)d_in[16];

    // ws layout: [0, 416KB) bf16 Wcat; then fp32 gates [B, GPAD]
    short* wcat  = (short*)d_ws;
    float* gates = (float*)((char*)d_ws + (size_t)GPAD * C_DIM * sizeof(short));

    float* out_w   = (float*)d_out;                      // [4096,256]
    float* out_mem = out_w + (size_t)B_DIM * N_DIM;      // [4096,256,64]

    build_wcat<<<(GPAD * C_DIM + 255) / 256, 256, 0, stream>>>(
        Wk, Wbeta, Wg, Ws, Wgamma, We, Wa, wcat);
    gates_gemm<<<B_DIM / 16, 64, 0, stream>>>(emb, wcat, gates);
    ntm_fused<<<B_DIM, 256, 0, stream>>>(w_prev, memory, gates,
                                         bk, bbeta, bg, bs, bgamma, be, ba,
                                         out_w, out_mem);
}